// Round 6
// baseline (102.397 us; speedup 1.0000x reference)
//
#include <hip/hip_runtime.h>
#include <math.h>

// y[t, j] = (t/n) * a3[j] + b3[j]
//   a  = W1eff[:, 0]                (128)    b  = W1eff[:, 1:] @ X   (128)
//   a2 = W2eff @ a                  (32)     b2 = W2eff @ b          (32)
//   a3 = W3eff @ a2                 (32)     b3 = W3eff @ b2         (32)
// ws float layout: a3[0:32], b3[32:64]

// Fast NAC weight: tanh(w)*sigmoid(m) via hardware exp.
// tanh(x) = 1 - 2/(exp(2x)+1)  (exact limits at +-inf), sigmoid via __expf.
__device__ __forceinline__ float nac_w_fast(float wh, float mh) {
    float t = 1.0f - 2.0f / (__expf(2.0f * wh) + 1.0f);
    float s = 1.0f / (1.0f + __expf(-mh));
    return t * s;
}

// Single block, 1024 threads (16 waves): whole coefficient chain in one launch.
__global__ __launch_bounds__(1024) void fp_coef(
        const float* __restrict__ X,
        const float* __restrict__ W1, const float* __restrict__ M1,
        const float* __restrict__ W2, const float* __restrict__ M2,
        const float* __restrict__ W3, const float* __restrict__ M3,
        float* __restrict__ ws) {
    __shared__ float sX[512];
    __shared__ float sA[128], sB[128];
    __shared__ float s2A[32], s2B[32];
    const int tid = threadIdx.x;
    const int wave = tid >> 6;
    const int lane = tid & 63;

    if (tid < 512) sX[tid] = (tid == 0) ? 0.0f : X[tid - 1];
    __syncthreads();

    // ---- stage 1: rows of W1 (128x512). 16 waves x 8 rows; lane covers 8 cols.
    #pragma unroll
    for (int r = 0; r < 8; ++r) {
        const int k = wave * 8 + r;
        const float* w1r = W1 + k * 512;
        const float* m1r = M1 + k * 512;
        float p = 0.0f;
        float w0 = 0.0f;
        #pragma unroll
        for (int m = 0; m < 8; ++m) {
            const int c = lane + m * 64;
            float w = nac_w_fast(w1r[c], m1r[c]);
            if (m == 0 && lane == 0) w0 = w;          // effective weight at col 0
            p = fmaf(w, sX[c], p);
        }
        #pragma unroll
        for (int d = 32; d >= 1; d >>= 1) p += __shfl_xor(p, d, 64);
        if (lane == 0) { sA[k] = w0; sB[k] = p; }
    }
    __syncthreads();

    // ---- stage 2: rows of W2 (32x128). 16 waves x 2 rows; lane covers 2 cols.
    #pragma unroll
    for (int r = 0; r < 2; ++r) {
        const int k = wave * 2 + r;
        float wA = nac_w_fast(W2[k * 128 + lane],      M2[k * 128 + lane]);
        float wB = nac_w_fast(W2[k * 128 + 64 + lane], M2[k * 128 + 64 + lane]);
        float pa = wA * sA[lane] + wB * sA[64 + lane];
        float pb = wA * sB[lane] + wB * sB[64 + lane];
        #pragma unroll
        for (int d = 32; d >= 1; d >>= 1) {
            pa += __shfl_xor(pa, d, 64);
            pb += __shfl_xor(pb, d, 64);
        }
        if (lane == 0) { s2A[k] = pa; s2B[k] = pb; }
    }
    __syncthreads();

    // ---- stage 3: rows of W3 (32x32). 16 waves x 2 rows; both 32-lane halves
    // compute redundantly (width-32 reduce keeps halves independent).
    #pragma unroll
    for (int r = 0; r < 2; ++r) {
        const int k = wave * 2 + r;
        const int col = lane & 31;
        float w = nac_w_fast(W3[k * 32 + col], M3[k * 32 + col]);
        float pa = w * s2A[col];
        float pb = w * s2B[col];
        #pragma unroll
        for (int d = 16; d >= 1; d >>= 1) {
            pa += __shfl_xor(pa, d, 32);
            pb += __shfl_xor(pb, d, 32);
        }
        if (lane == 0) { ws[k] = pa; ws[32 + k] = pb; }
    }
}

// Streaming writer: out[t*32 + j] = fma(t*inv_n, a3[j], b3[j]); float4 stores.
__global__ __launch_bounds__(256) void fp_writer(
        const float* __restrict__ coef,   // a3 at [0:32], b3 at [32:64]
        float* __restrict__ out,
        int T, float inv_n) {
    __shared__ float sA[32], sB[32];
    const int tid = threadIdx.x;
    if (tid < 32) { sA[tid] = coef[tid]; sB[tid] = coef[32 + tid]; }
    __syncthreads();

    const int total = T * 8;                       // float4 groups (32 floats/row)
    const int stride = gridDim.x * blockDim.x;     // multiple of 8 (blockDim=256)
    int idx = blockIdx.x * blockDim.x + tid;
    if (idx >= total) return;
    // idx % 8 is invariant across grid-stride iterations -> hoist coef reads.
    const int g = idx & 7;
    const int j = g * 4;
    const float a0 = sA[j], a1 = sA[j + 1], a2 = sA[j + 2], a3 = sA[j + 3];
    const float b0 = sB[j], b1 = sB[j + 1], b2 = sB[j + 2], b3 = sB[j + 3];
    float4* __restrict__ out4 = reinterpret_cast<float4*>(out);
    for (; idx < total; idx += stride) {
        const float tv = (float)(idx >> 3) * inv_n;
        float4 o;
        o.x = fmaf(tv, a0, b0);
        o.y = fmaf(tv, a1, b1);
        o.z = fmaf(tv, a2, b2);
        o.w = fmaf(tv, a3, b3);
        out4[idx] = o;
    }
}

extern "C" void kernel_launch(void* const* d_in, const int* in_sizes, int n_in,
                              void* d_out, int out_size, void* d_ws, size_t ws_size,
                              hipStream_t stream) {
    const float* X  = (const float*)d_in[0];
    const float* W1 = (const float*)d_in[1];
    const float* M1 = (const float*)d_in[2];
    const float* W2 = (const float*)d_in[3];
    const float* M2 = (const float*)d_in[4];
    const float* W3 = (const float*)d_in[5];
    const float* M3 = (const float*)d_in[6];
    float* out = (float*)d_out;
    float* ws  = (float*)d_ws;

    const int T = out_size / 32;                 // == n_steps (262144)
    const float inv_n = 1.0f / (float)T;         // T = 2^18, exact

    fp_coef<<<1, 1024, 0, stream>>>(X, W1, M1, W2, M2, W3, M3, ws);

    const int total = T * 8;
    int blocks = (total + 255) / 256;
    if (blocks > 2048) blocks = 2048;
    fp_writer<<<blocks, 256, 0, stream>>>(ws, out, T, inv_n);
}

// Round 7
// 93.583 us; speedup vs baseline: 1.0942x; 1.0942x over previous
//
#include <hip/hip_runtime.h>
#include <math.h>

// y[t, j] = (t/n) * a3[j] + b3[j]
//   a  = W1eff[:, 0]                (128)    b  = W1eff[:, 1:] @ X   (128)
//   a2 = W2eff @ a                  (32)     b2 = W2eff @ b          (32)
//   a3 = W3eff @ a2                 (32)     b3 = W3eff @ b2         (32)
// ws float layout: a[0:128], b[128:256], a3[256:288], b3[288:320]

// Fast NAC weight: tanh(w)*sigmoid(m) via hardware exp.
// tanh(x) = 1 - 2/(exp(2x)+1) (exact limits at +-inf), sigmoid via __expf.
__device__ __forceinline__ float nac_w_fast(float wh, float mh) {
    float t = 1.0f - 2.0f / (__expf(2.0f * wh) + 1.0f);
    float s = 1.0f / (1.0f + __expf(-mh));
    return t * s;
}

// 128 blocks (one per row of W1), 512 threads (one per column).
__global__ __launch_bounds__(512) void fp_s1(
        const float* __restrict__ X,
        const float* __restrict__ W1, const float* __restrict__ M1,
        float* __restrict__ ws) {
    const int k = blockIdx.x;      // row 0..127
    const int j = threadIdx.x;     // col 0..511
    const int idx = k * 512 + j;
    float w = nac_w_fast(W1[idx], M1[idx]);
    float xv = (j == 0) ? 0.0f : X[j - 1];
    float p = w * xv;
    #pragma unroll
    for (int d = 32; d >= 1; d >>= 1) p += __shfl_xor(p, d, 64);
    __shared__ float red[8];
    const int wave = j >> 6;
    if ((j & 63) == 0) red[wave] = p;
    __syncthreads();
    if (j == 0) {
        float bsum = 0.0f;
        #pragma unroll
        for (int w8 = 0; w8 < 8; ++w8) bsum += red[w8];
        ws[k] = w;            // a[k] (thread 0 holds eff weight of col 0)
        ws[128 + k] = bsum;   // b[k]
    }
}

// Stages 2+3 fused: 1 block, 256 threads (4 waves).
__global__ __launch_bounds__(256) void fp_s23(
        const float* __restrict__ W2, const float* __restrict__ M2,
        const float* __restrict__ W3, const float* __restrict__ M3,
        float* __restrict__ ws) {
    __shared__ float sA[128], sB[128];
    __shared__ float s2A[32], s2B[32];
    const int tid = threadIdx.x;
    const int wave = tid >> 6;
    const int lane = tid & 63;

    // Load a,b into LDS (128 each; threads 0..255 cover both).
    if (tid < 128) sA[tid] = ws[tid];
    else           sB[tid - 128] = ws[tid];
    __syncthreads();

    // Stage 2: a2/b2 = W2eff @ {a,b}. 4 waves x 8 rows; lane covers 2 cols.
    #pragma unroll
    for (int r = 0; r < 8; ++r) {
        const int k = wave * 8 + r;
        float wA = nac_w_fast(W2[k * 128 + lane],      M2[k * 128 + lane]);
        float wB = nac_w_fast(W2[k * 128 + 64 + lane], M2[k * 128 + 64 + lane]);
        float pa = wA * sA[lane] + wB * sA[64 + lane];
        float pb = wA * sB[lane] + wB * sB[64 + lane];
        #pragma unroll
        for (int d = 32; d >= 1; d >>= 1) {
            pa += __shfl_xor(pa, d, 64);
            pb += __shfl_xor(pb, d, 64);
        }
        if (lane == 0) { s2A[k] = pa; s2B[k] = pb; }
    }
    __syncthreads();

    // Stage 3: a3/b3 = W3eff @ {a2,b2}. 4 waves x 8 rows; both 32-lane
    // halves compute redundantly (width-32 reduce keeps halves independent).
    #pragma unroll
    for (int r = 0; r < 8; ++r) {
        const int k = wave * 8 + r;
        const int col = lane & 31;
        float w = nac_w_fast(W3[k * 32 + col], M3[k * 32 + col]);
        float pa = w * s2A[col];
        float pb = w * s2B[col];
        #pragma unroll
        for (int d = 16; d >= 1; d >>= 1) {
            pa += __shfl_xor(pa, d, 32);
            pb += __shfl_xor(pb, d, 32);
        }
        if (lane == 0) { ws[256 + k] = pa; ws[288 + k] = pb; }
    }
}

// Streaming writer: out[t*32 + j] = fma(t*inv_n, a3[j], b3[j]); float4 stores.
__global__ __launch_bounds__(256) void fp_writer(
        const float* __restrict__ coef,   // a3 at [0:32], b3 at [32:64]
        float* __restrict__ out,
        int T, float inv_n) {
    __shared__ float sA[32], sB[32];
    const int tid = threadIdx.x;
    if (tid < 32) { sA[tid] = coef[tid]; sB[tid] = coef[32 + tid]; }
    __syncthreads();

    const int total = T * 8;                       // float4 groups (32 floats/row)
    const int stride = gridDim.x * blockDim.x;     // multiple of 8 (blockDim=256)
    int idx = blockIdx.x * blockDim.x + tid;
    if (idx >= total) return;
    // idx % 8 invariant across grid-stride iterations -> hoist coef reads.
    const int g = idx & 7;
    const int j = g * 4;
    const float a0 = sA[j], a1 = sA[j + 1], a2 = sA[j + 2], a3 = sA[j + 3];
    const float b0 = sB[j], b1 = sB[j + 1], b2 = sB[j + 2], b3 = sB[j + 3];
    float4* __restrict__ out4 = reinterpret_cast<float4*>(out);
    for (; idx < total; idx += stride) {
        const float tv = (float)(idx >> 3) * inv_n;
        float4 o;
        o.x = fmaf(tv, a0, b0);
        o.y = fmaf(tv, a1, b1);
        o.z = fmaf(tv, a2, b2);
        o.w = fmaf(tv, a3, b3);
        out4[idx] = o;
    }
}

extern "C" void kernel_launch(void* const* d_in, const int* in_sizes, int n_in,
                              void* d_out, int out_size, void* d_ws, size_t ws_size,
                              hipStream_t stream) {
    const float* X  = (const float*)d_in[0];
    const float* W1 = (const float*)d_in[1];
    const float* M1 = (const float*)d_in[2];
    const float* W2 = (const float*)d_in[3];
    const float* M2 = (const float*)d_in[4];
    const float* W3 = (const float*)d_in[5];
    const float* M3 = (const float*)d_in[6];
    float* out = (float*)d_out;
    float* ws  = (float*)d_ws;

    const int T = out_size / 32;                 // == n_steps (262144)
    const float inv_n = 1.0f / (float)T;         // T = 2^18, exact

    fp_s1<<<128, 512, 0, stream>>>(X, W1, M1, ws);
    fp_s23<<<1, 256, 0, stream>>>(W2, M2, W3, M3, ws);

    const int total = T * 8;
    int blocks = (total + 255) / 256;
    if (blocks > 2048) blocks = 2048;
    fp_writer<<<blocks, 256, 0, stream>>>(ws + 256, out, T, inv_n);
}